// Round 10
// baseline (6911.292 us; speedup 1.0000x reference)
//
#include <hip/hip_runtime.h>
#include <math.h>

// RipsLayer: dim-0 persistence of Rips filtration on 4096 points in R^64.
// R10: Boruvka MST (parallel, on-the-fly distances) + exact Prim-order replay
// on the sparse MST, single wave. Replay chain shortened: packed fixed-stride
// adjacency (deg embedded, dummy-padded), batched LDS reads, exact-init
// cache, buffered coalesced death stores.

#define N 4096
#define INF __builtin_huge_valf()
#define INFBITS 0x7f800000u
#define NINFBITS 0xff800000u
typedef unsigned long long ull;

// ---------------------------------------------------------------------------
struct WS {
    unsigned comp[N];
    unsigned par[N];
    unsigned tgt[N];
    ull      minedge[N];   // (dbits<<24)|(j<<12)|i
    ull      ebuf[N];
    unsigned ecnt;
    unsigned done;
    unsigned pad[2];
    unsigned off[N + 4];   // CSR offsets
    ull      adj[2 * N];   // CSR entries: (wbits<<32)|nbr
    ull      adj4[4 * N];  // packed: slot0 low word = nbr | (deg<<16)
};

// ---------------------------------------------------------------------------
__global__ __launch_bounds__(1024) void k_init(WS* W) {
    int v = blockIdx.x * 1024 + threadIdx.x;
    if (v < N) {
        W->comp[v] = (unsigned)v;
        W->minedge[v] = ~0ull;
    }
    if (blockIdx.x == 0 && threadIdx.x == 0) { W->ecnt = 0; W->done = 0; }
}

// ---------------------------------------------------------------------------
// k_minedge: per-vertex min external edge key, distances on the fly.
// ---------------------------------------------------------------------------
__global__ __launch_bounds__(256) void k_minedge(const float* __restrict__ x,
                                                 WS* __restrict__ W) {
    if (W->done) return;
    __shared__ float As[64][68];
    __shared__ float Bs[64][68];
    __shared__ ull red[64][17];
    const int t = threadIdx.x;
    const int bi = blockIdx.y * 64;
    const int jp = blockIdx.x * 512;

#pragma unroll
    for (int g = 0; g < 4; ++g) {
        int idx = t + 256 * g;
        int row = idx >> 4;
        int k4 = (idx & 15) << 2;
        *(float4*)(&As[row][k4]) =
            *(const float4*)(x + (size_t)(bi + row) * 64 + k4);
    }

    const int ti = (t >> 4) << 2;
    const int tj = (t & 15) << 2;
    unsigned ci[4];
#pragma unroll
    for (int r = 0; r < 4; ++r) ci[r] = W->comp[bi + ti + r];

    ull rk[4] = {~0ull, ~0ull, ~0ull, ~0ull};

    for (int tile = 0; tile < 8; ++tile) {
        const int jb = jp + tile * 64;
        __syncthreads();
#pragma unroll
        for (int g = 0; g < 4; ++g) {
            int idx = t + 256 * g;
            int row = idx >> 4;
            int k4 = (idx & 15) << 2;
            *(float4*)(&Bs[row][k4]) =
                *(const float4*)(x + (size_t)(jb + row) * 64 + k4);
        }
        __syncthreads();
        unsigned cj[4];
#pragma unroll
        for (int c = 0; c < 4; ++c) cj[c] = W->comp[jb + tj + c];

        float acc[4][4];
#pragma unroll
        for (int r = 0; r < 4; ++r)
#pragma unroll
            for (int c = 0; c < 4; ++c) acc[r][c] = 0.0f;
        for (int k = 0; k < 64; k += 4) {
            float4 a[4], b[4];
#pragma unroll
            for (int r = 0; r < 4; ++r) a[r] = *(const float4*)(&As[ti + r][k]);
#pragma unroll
            for (int c = 0; c < 4; ++c) b[c] = *(const float4*)(&Bs[tj + c][k]);
#pragma unroll
            for (int r = 0; r < 4; ++r)
#pragma unroll
                for (int c = 0; c < 4; ++c) {
                    float d0 = a[r].x - b[c].x;
                    float d1 = a[r].y - b[c].y;
                    float d2 = a[r].z - b[c].z;
                    float d3 = a[r].w - b[c].w;
                    float s = acc[r][c];
                    s = fmaf(d0, d0, s);
                    s = fmaf(d1, d1, s);
                    s = fmaf(d2, d2, s);
                    s = fmaf(d3, d3, s);
                    acc[r][c] = s;
                }
        }
#pragma unroll
        for (int r = 0; r < 4; ++r)
#pragma unroll
            for (int c = 0; c < 4; ++c) {
                if (ci[r] != cj[c]) {
                    float d = sqrtf(fmaxf(acc[r][c], 1e-12f));
                    ull key = ((ull)__float_as_uint(d) << 24) |
                              ((ull)(unsigned)(jb + tj + c) << 12) |
                              (ull)(unsigned)(bi + ti + r);
                    if (key < rk[r]) rk[r] = key;
                }
            }
    }
    __syncthreads();
#pragma unroll
    for (int r = 0; r < 4; ++r) red[ti + r][t & 15] = rk[r];
    __syncthreads();
    if (t < 64) {
        ull k = red[t][0];
#pragma unroll
        for (int c = 1; c < 16; ++c) {
            ull o = red[t][c];
            if (o < k) k = o;
        }
        if (k != ~0ull) atomicMin(&W->minedge[W->comp[bi + t]], k);
    }
}

// ---------------------------------------------------------------------------
__global__ __launch_bounds__(1024) void k_hook(WS* __restrict__ W) {
    if (W->done) return;
    const int t = threadIdx.x;
    __shared__ unsigned cnt[1024];

#pragma unroll
    for (int k = 0; k < 4; ++k) {
        int v = t + 1024 * k;
        W->tgt[v] = 0xffffffffu;
        W->par[v] = W->comp[v];
    }
    __syncthreads();
#pragma unroll
    for (int k = 0; k < 4; ++k) {
        int v = t + 1024 * k;
        if (W->comp[v] == (unsigned)v) {
            ull me = W->minedge[v];
            if (me != ~0ull) {
                unsigned j = (unsigned)(me >> 12) & 0xfffu;
                W->tgt[v] = W->comp[j];
            }
        }
    }
    __syncthreads();
#pragma unroll
    for (int k = 0; k < 4; ++k) {
        int v = t + 1024 * k;
        unsigned u = W->tgt[v];
        if (u != 0xffffffffu) {
            bool mutual = (W->tgt[u] == (unsigned)v);
            if (!(mutual && (unsigned)v < u)) {
                W->par[v] = u;
                unsigned idx = atomicAdd(&W->ecnt, 1u);
                W->ebuf[idx] = W->minedge[v];
            }
        }
    }
    __syncthreads();
    for (int it = 0; it < 12; ++it) {
#pragma unroll
        for (int k = 0; k < 4; ++k) {
            int v = t + 1024 * k;
            W->par[v] = W->par[W->par[v]];
        }
        __syncthreads();
    }
#pragma unroll
    for (int k = 0; k < 4; ++k) {
        int v = t + 1024 * k;
        W->comp[v] = W->par[v];
    }
    __syncthreads();
    unsigned c = 0;
#pragma unroll
    for (int k = 0; k < 4; ++k) {
        int v = t + 1024 * k;
        c += (W->comp[v] == (unsigned)v);
    }
    cnt[t] = c;
    __syncthreads();
    for (int st = 512; st > 0; st >>= 1) {
        if (t < st) cnt[t] += cnt[t + st];
        __syncthreads();
    }
    if (t == 0 && cnt[0] == 1u) W->done = 1u;
#pragma unroll
    for (int k = 0; k < 4; ++k) W->minedge[t + 1024 * k] = ~0ull;
}

// ---------------------------------------------------------------------------
__global__ __launch_bounds__(1024) void k_csr(WS* __restrict__ W) {
    __shared__ unsigned deg[N];
    __shared__ unsigned ps[1024];
    const int t = threadIdx.x;
#pragma unroll
    for (int k = 0; k < 4; ++k) deg[t + 1024 * k] = 0;
    __syncthreads();
#pragma unroll
    for (int k = 0; k < 4; ++k) {
        int e = t + 1024 * k;
        if (e < N - 1) {
            ull key = W->ebuf[e];
            unsigned i = (unsigned)key & 0xfffu;
            unsigned j = (unsigned)(key >> 12) & 0xfffu;
            atomicAdd(&deg[i], 1u);
            atomicAdd(&deg[j], 1u);
        }
    }
    __syncthreads();
    unsigned a0 = deg[4 * t], a1 = deg[4 * t + 1];
    unsigned a2 = deg[4 * t + 2], a3 = deg[4 * t + 3];
    ps[t] = a0 + a1 + a2 + a3;
    __syncthreads();
    for (int d = 1; d < 1024; d <<= 1) {
        unsigned v = (t >= d) ? ps[t - d] : 0u;
        __syncthreads();
        ps[t] += v;
        __syncthreads();
    }
    unsigned base = (t > 0) ? ps[t - 1] : 0u;
    unsigned o0 = base, o1 = o0 + a0, o2 = o1 + a1, o3 = o2 + a2;
    W->off[4 * t] = o0; W->off[4 * t + 1] = o1;
    W->off[4 * t + 2] = o2; W->off[4 * t + 3] = o3;
    deg[4 * t] = o0; deg[4 * t + 1] = o1;
    deg[4 * t + 2] = o2; deg[4 * t + 3] = o3;
    if (t == 1023) W->off[N] = ps[1023];
    __syncthreads();
#pragma unroll
    for (int k = 0; k < 4; ++k) {
        int e = t + 1024 * k;
        if (e < N - 1) {
            ull key = W->ebuf[e];
            unsigned i = (unsigned)key & 0xfffu;
            unsigned j = (unsigned)(key >> 12) & 0xfffu;
            unsigned wb = (unsigned)(key >> 24);
            unsigned p = atomicAdd(&deg[i], 1u);
            W->adj[p] = ((ull)wb << 32) | j;
            unsigned q = atomicAdd(&deg[j], 1u);
            W->adj[q] = ((ull)wb << 32) | i;
        }
    }
}

// ---------------------------------------------------------------------------
// k_pack: fixed-stride adjacency adj4[v][4]; slot0 low word embeds deg<<16;
// unused slots = (INFBITS<<32)|0 (provably a no-op vs an exact cache).
// ---------------------------------------------------------------------------
__global__ __launch_bounds__(1024) void k_pack(WS* __restrict__ W) {
    const int t = threadIdx.x;
#pragma unroll
    for (int k = 0; k < 4; ++k) {
        int v = t + 1024 * k;
        unsigned o = W->off[v];
        unsigned dg = W->off[v + 1] - o;
        ull s0 = W->adj[o] | ((ull)dg << 16);  // deg >= 1 for every MST vertex
        ull s1 = (dg > 1) ? W->adj[o + 1] : ((ull)INFBITS << 32);
        ull s2 = (dg > 2) ? W->adj[o + 2] : ((ull)INFBITS << 32);
        ull s3 = (dg > 3) ? W->adj[o + 3] : ((ull)INFBITS << 32);
        ull* d = &W->adj4[4 * (unsigned)v];
        d[0] = s0; d[1] = s1; d[2] = s2; d[3] = s3;
    }
}

// ---------------------------------------------------------------------------
// k_replay: exact Prim order on the MST, single wave.
// Lane L owns cols [64L,64L+64) = 8 groups of 8; cache[g] = EXACT argmin key
// ((mapped<<32)|col) of group g. mindb: f32 bits, removed = NINFBITS.
// ---------------------------------------------------------------------------
#define DPP_UMIN_STEP(x, ctrl)                                                 \
    {                                                                          \
        unsigned _o = (unsigned)__builtin_amdgcn_update_dpp(                   \
            0x7fffffff, (int)(x), ctrl, 0xF, 0xF, false);                      \
        x = (_o < (x)) ? _o : (x);                                             \
    }

__device__ __forceinline__ void relax4(ull cache[8], unsigned* mindb, int L,
                                       ull e0, ull e1, ull e2, ull e3) {
    unsigned n[4] = {(unsigned)e0 & 0xFFFu, (unsigned)e1 & 0xFFFu,
                     (unsigned)e2 & 0xFFFu, (unsigned)e3 & 0xFFFu};
    unsigned w[4] = {(unsigned)(e0 >> 32), (unsigned)(e1 >> 32),
                     (unsigned)(e2 >> 32), (unsigned)(e3 >> 32)};
    // batch the 4 LDS reads (independent, overlap their latency)
    unsigned m[4];
#pragma unroll
    for (int k = 0; k < 4; ++k) m[k] = mindb[n[k]];
#pragma unroll
    for (int k = 0; k < 4; ++k) {
        float f = fminf(__uint_as_float(m[k]), __uint_as_float(w[k]));
        unsigned b = __float_as_uint(f);
        bool own = (int)(n[k] >> 6) == L;
        if (own) mindb[n[k]] = b;
        unsigned mm = (b == NINFBITS) ? INFBITS : b;
        ull kk = ((ull)mm << 32) | n[k];
        if (own) {
            unsigned sl = (n[k] >> 3) & 7u;
#pragma unroll
            for (unsigned u = 0; u < 8; ++u)
                if (sl == u) cache[u] = (kk < cache[u]) ? kk : cache[u];
        }
    }
}

__global__ __launch_bounds__(64) void k_replay(const WS* __restrict__ W,
                                               float* __restrict__ out) {
    __shared__ unsigned mindb[N];
    const int L = threadIdx.x;

#pragma unroll
    for (int q = 0; q < 16; ++q) {
        uint4 v = {INFBITS, INFBITS, INFBITS, INFBITS};
        *(uint4*)&mindb[64 * L + 4 * q] = v;
    }
    ull cache[8];
#pragma unroll
    for (int g = 0; g < 8; ++g)
        cache[g] = ((ull)INFBITS << 32) | (unsigned)(64 * L + 8 * g);  // exact
    __syncthreads();

    // seed: vertex 0 (group-0 min key unchanged: all-INF maps to (INF,0))
    if (L == 0) mindb[0] = NINFBITS;
    __asm__ __volatile__("" ::: "memory");
    {
        const ull* a4 = &W->adj4[0];
        ull e0 = a4[0], e1 = a4[1], e2 = a4[2], e3 = a4[3];
        unsigned dg = ((unsigned)e0 >> 16) & 0xFFFu;
        relax4(cache, mindb, L, e0, e1, e2, e3);
        if (__builtin_amdgcn_readfirstlane((int)dg) > 4) {
            unsigned o = W->off[0];
            for (unsigned k = 4; k < dg; ++k) {
                ull e = W->adj[o + k];
                relax4(cache, mindb, L, e, (ull)INFBITS << 32,
                       (ull)INFBITS << 32, (ull)INFBITS << 32);
            }
        }
    }
    __asm__ __volatile__("" ::: "memory");

    float bd = 0.0f;  // buffered death for step k with (k&63)==L

#pragma unroll 1
    for (int s = 1; s < N; ++s) {
        // ---- argmin: 8-key u64 tree -> u32 DPP on value -> ballot col ----
        ull b0 = cache[0] < cache[1] ? cache[0] : cache[1];
        ull b1 = cache[2] < cache[3] ? cache[2] : cache[3];
        ull b2 = cache[4] < cache[5] ? cache[4] : cache[5];
        ull b3 = cache[6] < cache[7] ? cache[6] : cache[7];
        ull b4 = b0 < b1 ? b0 : b1;
        ull b5 = b2 < b3 ? b2 : b3;
        ull bk = b4 < b5 ? b4 : b5;
        unsigned lv = (unsigned)(bk >> 32);

        unsigned xm = lv;
        DPP_UMIN_STEP(xm, 0x111);
        DPP_UMIN_STEP(xm, 0x112);
        DPP_UMIN_STEP(xm, 0x114);
        DPP_UMIN_STEP(xm, 0x118);
        DPP_UMIN_STEP(xm, 0x142);
        DPP_UMIN_STEP(xm, 0x143);
        unsigned wm = (unsigned)__builtin_amdgcn_readlane((int)xm, 63);
        ull tied = __ballot(lv == wm);
        int src = __ffsll(tied) - 1;  // lowest lane == lowest col (blocked)
        unsigned j =
            (unsigned)__builtin_amdgcn_readlane((int)(unsigned)bk, src);

        // ---- buffered death capture; coalesced flush every 64 steps ----
        const int k = s - 1;
        bd = ((unsigned)(k & 63) == (unsigned)L) ? __uint_as_float(wm) : bd;
        if ((k & 63) == 63)
            *(float2*)(out + 2 * ((k & ~63) + L)) = make_float2(0.0f, bd);

        // ---- issue adjacency load + group reads together ----
        const ull* a4 = &W->adj4[4 * j];
        ull e0 = a4[0], e1 = a4[1], e2 = a4[2], e3 = a4[3];
        unsigned gbase = (j >> 3) << 3;
        uint4 ga = *(const uint4*)&mindb[gbase];
        uint4 gb = *(const uint4*)&mindb[gbase + 4];

        // ---- removal: owner pins j and rebuilds that group's cache ----
        if ((int)(j >> 6) == L) {
            mindb[j] = NINFBITS;
            unsigned vals[8] = {ga.x, ga.y, ga.z, ga.w,
                                gb.x, gb.y, gb.z, gb.w};
            ull nk = ~0ull;
#pragma unroll
            for (unsigned u = 0; u < 8; ++u) {
                unsigned m = vals[u];
                if (u == (j & 7u)) m = INFBITS;
                if (m == NINFBITS) m = INFBITS;
                ull kk = ((ull)m << 32) | (gbase + u);
                if (kk < nk) nk = kk;
            }
            unsigned sl = (j >> 3) & 7u;
#pragma unroll
            for (unsigned u = 0; u < 8; ++u)
                if (u == sl) cache[u] = nk;
        }
        __asm__ __volatile__("" ::: "memory");

        // ---- relax the (<=4 fast-path) MST neighbors of j ----
        unsigned dg = ((unsigned)e0 >> 16) & 0xFFFu;
        relax4(cache, mindb, L, e0, e1, e2, e3);
        if (__builtin_amdgcn_readfirstlane((int)dg) > 4) {
            unsigned o = W->off[j];
            for (unsigned kk2 = 4; kk2 < dg; ++kk2) {
                ull e = W->adj[o + kk2];
                relax4(cache, mindb, L, e, (ull)INFBITS << 32,
                       (ull)INFBITS << 32, (ull)INFBITS << 32);
            }
        }
        __asm__ __volatile__("" ::: "memory");
    }

    // final partial flush: deaths k = 4032..4094 (lanes 0..62)
    if (L < 63) *(float2*)(out + 2 * (4032 + L)) = make_float2(0.0f, bd);
}

// ---------------------------------------------------------------------------
extern "C" void kernel_launch(void* const* d_in, const int* in_sizes, int n_in,
                              void* d_out, int out_size, void* d_ws, size_t ws_size,
                              hipStream_t stream) {
    const float* x = (const float*)d_in[0];
    float* out = (float*)d_out;  // [N-1][2]: (birth=0, death)
    WS* W = (WS*)d_ws;           // ~350 KB scratch

    k_init<<<4, 1024, 0, stream>>>(W);
    for (int r = 0; r < 12; ++r) {
        k_minedge<<<dim3(8, 64), 256, 0, stream>>>(x, W);
        k_hook<<<1, 1024, 0, stream>>>(W);
    }
    k_csr<<<1, 1024, 0, stream>>>(W);
    k_pack<<<1, 1024, 0, stream>>>(W);
    k_replay<<<1, 64, 0, stream>>>(W, out);
}